// Round 11
// baseline (1032.650 us; speedup 1.0000x reference)
//
#include <hip/hip_runtime.h>

constexpr int B = 64, T = 128, M = 8, KLEAF = 5, KR = 6, N = 48, E = 16, H = 32;
constexpr int BNR = B * N;              // 3072 rows
constexpr int NG  = B * T;              // 8192 graphs
constexpr int BNP = 16;                 // BN stat partitions
constexpr long long R_SIZE = (long long)B * T * N * H;  // 12582912

#define DEVI __device__ __forceinline__

typedef float nf4 __attribute__((ext_vector_type(4)));   // native vec4 for NT builtins

DEVI float frcp(float x) { return __builtin_amdgcn_rcpf(x); }
DEVI float sigm(float x) { return frcp(1.f + __expf(-x)); }
DEVI float tanh_(float x) {
  float a = __expf(2.f * fabsf(x));
  float r = 1.f - 2.f * frcp(a + 1.f);
  return x >= 0.f ? r : -r;
}

DEVI void nt_store4(const float4& v, float* p) {
  nf4 t; t.x = v.x; t.y = v.y; t.z = v.z; t.w = v.w;
  __builtin_nontemporal_store(t, (nf4*)p);
}

// ------ K1: root agg + phi MLP + fused XW1 = v @ spa_wih^T → xw (T,BNR,128) --
// xw stores are NONTEMPORAL: 201 MB stream must not thrash L2 (R9 post-mortem:
// cached xw stream evicted weights for every k_gat block -> 360 MB refetch).
__global__ __launch_bounds__(256, 4) void k_phi(
    const float* __restrict__ feat, const float* __restrict__ w1,
    const float* __restrict__ b1, const float* __restrict__ w2,
    const float* __restrict__ b2, const float* __restrict__ wih,
    float* __restrict__ xw)
{
  __shared__ float wT[E][128];           // wT[e][g] = wih[g*E+e]  (8 KB)
  int tid = threadIdx.x;
  for (int i = tid; i < E * 128; i += 256) {
    int e = i >> 7, g = i & 127;
    wT[e][g] = wih[g * E + e];
  }
  int gid = blockIdx.x * 256 + tid;      // grid is exact: B*T*N = 1536*256
  int nn = gid % N;
  int bt = gid / N;
  int m = nn / KR, k = nn % KR;
  int t = bt % T, b = bt / T;
  const float* fp = feat + ((size_t)bt * M + m) * (KLEAF * 3);
  float x0, x1, x2;
  if (k < KLEAF) {
    x0 = fp[k * 3 + 0]; x1 = fp[k * 3 + 1]; x2 = fp[k * 3 + 2];
  } else {
    float sx = 0.f, sy = 0.f, sw = 0.f, av = 0.f;
#pragma unroll
    for (int kp = 0; kp < KLEAF; kp++) {
      float fx = fp[kp * 3], fy = fp[kp * 3 + 1], fv = fp[kp * 3 + 2];
      float w = fv > 0.5f ? 1.f : 0.f;
      sx += fx * w; sy += fy * w; sw += w; av = fmaxf(av, w);
    }
    float dn = fmaxf(sw, 1.f);
    x0 = sx / dn; x1 = sy / dn; x2 = av;
  }
  float hd[E];
#pragma unroll
  for (int e = 0; e < E; e++) {
    float v = b1[e] + x0 * w1[0 * E + e] + x1 * w1[1 * E + e] + x2 * w1[2 * E + e];
    hd[e] = v > 0.f ? v : 0.f;
  }
  float vv[E];
#pragma unroll
  for (int e2 = 0; e2 < E; e2++) {
    float acc = b2[e2];
#pragma unroll
    for (int e = 0; e < E; e++) acc += hd[e] * w2[e * E + e2];
    vv[e2] = acc;
  }
  __syncthreads();
  // xw row = v @ wT  (128 gates, 4 passes of 32)
  float* xo = xw + ((size_t)t * BNR + b * N + nn) * 128;
  for (int pass = 0; pass < 4; pass++) {
    float4 a4[8];
#pragma unroll
    for (int c = 0; c < 8; c++) a4[c] = make_float4(0.f, 0.f, 0.f, 0.f);
#pragma unroll
    for (int e = 0; e < E; e++) {
      float ve = vv[e];
      const float4* wr = (const float4*)&wT[e][pass * 32];
#pragma unroll
      for (int c = 0; c < 8; c++) {
        float4 w4 = wr[c];
        a4[c].x += ve * w4.x; a4[c].y += ve * w4.y;
        a4[c].z += ve * w4.z; a4[c].w += ve * w4.w;
      }
    }
#pragma unroll
    for (int c = 0; c < 8; c++)
      nt_store4(a4[c], xo + (pass * 8 + c) * 4);
  }
}

// ------- K2/K5: LSTM recurrence only (x-projection precomputed in xw) --------
// xw reads NONTEMPORAL (one-shot stream). h-half of dout (php) is never read
// again -> NT store. pr (r output) is re-read by bn/gat -> cached store.
template <int MODE>
__global__ __launch_bounds__(256, 6) void k_lstm(
    const float* __restrict__ xw, const float* __restrict__ whh,
    const float* __restrict__ bih, const float* __restrict__ bhh,
    float* __restrict__ dout)
{
  int tid = threadIdx.x;
  int wave = tid >> 6;
  int pr_ = wave >> 1;          // row within block (0,1)
  int wsel = wave & 1;          // 0: {i,f}  1: {g,o}
  int lane = tid & 63;
  int j = lane & 31, hi = lane >> 5;
  int row = blockIdx.x * 2 + pr_;
  int b = row / N, n = row % N;
  int gate = wsel * 64 + hi * 32 + j;

  float Wh[32];
#pragma unroll
  for (int k = 0; k < 32; k++) Wh[k] = whh[gate * 32 + k];
  float bs = bih[gate] + bhh[gate];

  __shared__ __align__(16) float hl[4][32];   // per-wave h copy
  __shared__ float gx[2][2][2][2][32];        // [pr][par][wsel][hi][j]
  if (hi == 0) hl[wave][j] = 0.f;             // own-wave init, in-order DS

  const float* xpt = xw + (size_t)row * 128 + gate;
  float xc = __builtin_nontemporal_load(xpt); // t = 0
  xpt += (size_t)BNR * 128;

  float c = 0.f;
  float* prp = dout + ((size_t)b * T * N + n) * H + j;
  float* php = dout + R_SIZE + ((size_t)b * T * N + n) * 2 * H + (MODE == 1 ? H : 0) + j;

  for (int t = 0; t < T; t++) {
    int par = t & 1;
    float xn = 0.f;
    if (t < T - 1) {
      xn = __builtin_nontemporal_load(xpt);
      xpt += (size_t)BNR * 128;
    }
    float a0 = bs + xc, a1 = 0.f, a2 = 0.f, a3 = 0.f;
    const float4* hp4 = (const float4*)hl[wave];
#pragma unroll
    for (int q = 0; q < 8; q++) {
      float4 hv = hp4[q];                     // ds_read_b128 broadcast
      a0 += Wh[4 * q + 0] * hv.x; a1 += Wh[4 * q + 1] * hv.y;
      a2 += Wh[4 * q + 2] * hv.z; a3 += Wh[4 * q + 3] * hv.w;
    }
    float a = (a0 + a1) + (a2 + a3);
    float act = (wsel == 0) ? sigm(a) : (hi ? sigm(a) : tanh_(a));
    gx[pr_][par][wsel][hi][j] = act;
    __syncthreads();
    if (hi == 0) {
      float iv = gx[pr_][par][0][0][j];
      float fv = gx[pr_][par][0][1][j];
      float gv = gx[pr_][par][1][0][j];
      float ov = gx[pr_][par][1][1][j];
      c = fv * c + iv * gv;
      float hnew = ov * tanh_(c);
      hl[wave][j] = hnew;                     // own-wave write
      if (wsel == 0) {
        if (MODE == 0) {
          *prp = hnew;
          __builtin_nontemporal_store(hnew, php);
        } else {
          __builtin_nontemporal_store(hnew, php);
        }
      }
    }
    xc = xn;
    prp += N * H; php += N * 2 * H;
  }
}

// ---------------- K3a: BN partial stats per (t, partition) -------------------
__global__ __launch_bounds__(256) void k_bn1(
    const float* __restrict__ r, float* __restrict__ part)
{
  int t = blockIdx.x, p = blockIdx.y;
  int c = threadIdx.x & 31, rg = threadIdx.x >> 5;
  constexpr int RPP = BNR / BNP;   // 192 rows per partition
  float s = 0.f, s2 = 0.f;
  for (int row = p * RPP + rg; row < (p + 1) * RPP; row += 8) {
    int b = row / N, n = row % N;
    float x = r[((size_t)b * T + t) * N * H + (size_t)n * H + c];
    s += x; s2 += x * x;
  }
  __shared__ float sm[2][8][32];
  sm[0][rg][c] = s; sm[1][rg][c] = s2;
  __syncthreads();
  if (rg == 0) {
    float ss = 0.f, ss2 = 0.f;
#pragma unroll
    for (int i = 0; i < 8; i++) { ss += sm[0][i][c]; ss2 += sm[1][i][c]; }
    part[((size_t)t * BNP + p) * 64 + c] = ss;
    part[((size_t)t * BNP + p) * 64 + 32 + c] = ss2;
  }
}

// ---------------- K3b: finalize BN scale/shift table (T, 2, 32) --------------
__global__ void k_bn2(
    const float* __restrict__ part, const float* __restrict__ gamma,
    const float* __restrict__ beta, float* __restrict__ sctab)
{
  int t = blockIdx.x, c = threadIdx.x;   // 32 threads
  float ss = 0.f, ss2 = 0.f;
#pragma unroll
  for (int p = 0; p < BNP; p++) {
    ss  += part[((size_t)t * BNP + p) * 64 + c];
    ss2 += part[((size_t)t * BNP + p) * 64 + 32 + c];
  }
  float mu = ss * (1.f / BNR);
  float var = ss2 * (1.f / BNR) - mu * mu;
  float rstd = rsqrtf(var + 1e-5f);
  float sc = gamma[c] * rstd;
  sctab[t * 64 + c] = sc;
  sctab[t * 64 + 32 + c] = beta[c] - mu * sc;
}

// --- K4: BN-apply + 2x GAT + fused XW2 = rhat @ temp_wih^T → xw (T,BNR,128) --
// launch_bounds(256,2): VGPR cap 256 — the R9 (256,4)/cap-128 build spilled the
// XW2 epilogue working set to scratch (~670 MB of HBM write amplification).
// xw epilogue stores NONTEMPORAL.
__global__ __launch_bounds__(256, 2) void k_gat(
    const float* __restrict__ r, const float* __restrict__ sctab,
    const float* __restrict__ w1, const float* __restrict__ a1, const float* __restrict__ bg1,
    const float* __restrict__ w2, const float* __restrict__ a2, const float* __restrict__ bg2,
    const float* __restrict__ twih, float* __restrict__ xw)
{
  int g = blockIdx.x;          // b*T + t
  int b = g >> 7, t = g & 127;
  int tid = threadIdx.x;
  __shared__ float X[N][H];
  __shared__ float Hm[N][H + 1];   // padded: row-reads conflict-free
  __shared__ float Wl[H * H];
  __shared__ float wT2[H][128];    // wT2[k][g] = twih[g*32+k]  (16 KB)
  __shared__ float ssrc[N], sdst[N];
  __shared__ float alph[M][12];
  for (int i = tid; i < N * H; i += 256) {
    int cc = i & 31;
    ((float*)X)[i] = r[(size_t)g * N * H + i] * sctab[t * 64 + cc] + sctab[t * 64 + 32 + cc];
  }
  for (int i = tid; i < H * 128; i += 256) {
    int k = i >> 7, gg = i & 127;
    wT2[k][gg] = twih[gg * H + k];
  }
  const float* Ws[2] = {w1, w2};
  const float* As[2] = {a1, a2};
  const float* Bs[2] = {bg1, bg2};
  int oc = tid & 31, n0 = tid >> 5;
  for (int layer = 0; layer < 2; layer++) {
    const float* av = As[layer];
    const float* bias = Bs[layer];
    for (int i = tid; i < H * H; i += 256) Wl[i] = Ws[layer][i];
    __syncthreads();
    // h = X @ W  (48x32 @ 32x32)
#pragma unroll
    for (int rep = 0; rep < 6; rep++) {
      int n = n0 + rep * 8;
      float acc = 0.f;
#pragma unroll
      for (int kk = 0; kk < H; kk++) acc += X[n][kk] * Wl[kk * H + oc];
      Hm[n][oc] = acc;
    }
    __syncthreads();
    if (tid < N) {
      float as = 0.f, ad = 0.f;
#pragma unroll
      for (int kk = 0; kk < H; kk++) {
        float x = Hm[tid][kk];
        as += x * av[kk]; ad += x * av[H + kk];
      }
      ssrc[tid] = as; sdst[tid] = ad;
    }
    __syncthreads();
    if (tid < M) {   // softmax over each root's 12 incoming edges
      float ev[12];
      float sd = sdst[tid * KR + KR - 1];
#pragma unroll
      for (int kp = 0; kp < KLEAF; kp++) ev[kp] = ssrc[tid * KR + kp] + sd;
#pragma unroll
      for (int j = 0; j < 7; j++) {
        int mm = j < tid ? j : j + 1;
        ev[KLEAF + j] = ssrc[mm * KR + KR - 1] + sd;
      }
      float mx = -1e30f;
#pragma unroll
      for (int i = 0; i < 12; i++) {
        float e = ev[i]; e = e > 0.f ? e : 0.2f * e;
        ev[i] = e; mx = fmaxf(mx, e);
      }
      float s = 0.f;
#pragma unroll
      for (int i = 0; i < 12; i++) { float e = __expf(ev[i] - mx); ev[i] = e; s += e; }
      float inv = frcp(s);
#pragma unroll
      for (int i = 0; i < 12; i++) alph[tid][i] = ev[i] * inv;
    }
    __syncthreads();
    float hv[6];
#pragma unroll
    for (int rep = 0; rep < 6; rep++) {
      int n = n0 + rep * 8;
      int m2 = n / KR;
      float acc;
      if (n % KR == KR - 1) {      // root: attention-weighted sum of 12 srcs
        acc = 0.f;
#pragma unroll
        for (int kp = 0; kp < KLEAF; kp++) acc += alph[m2][kp] * Hm[m2 * KR + kp][oc];
#pragma unroll
        for (int j = 0; j < 7; j++) {
          int mm = j < m2 ? j : j + 1;
          acc += alph[m2][KLEAF + j] * Hm[mm * KR + KR - 1][oc];
        }
      } else {                      // leaf: single incoming edge, alpha == 1
        acc = Hm[m2 * KR + KR - 1][oc];
      }
      acc += bias[oc];
      hv[rep] = acc > 0.f ? acc : __expf(acc) - 1.f;   // elu
    }
    __syncthreads();
#pragma unroll
    for (int rep = 0; rep < 6; rep++) X[n0 + rep * 8][oc] = hv[rep];
    __syncthreads();
  }
  // XW2 epilogue: xw[t][b*N+n][0:128] = X[n][:] @ wT2  (rhat is in X)
  int g4 = tid & 31;            // float4 column 0..31
  int nb = tid >> 5;            // 0..7
  float4 acc[6];
#pragma unroll
  for (int rp = 0; rp < 6; rp++) acc[rp] = make_float4(0.f, 0.f, 0.f, 0.f);
  for (int kc = 0; kc < 4; kc++) {
    float4 w4r[8];
#pragma unroll
    for (int k8 = 0; k8 < 8; k8++) w4r[k8] = ((const float4*)wT2[kc * 8 + k8])[g4];
#pragma unroll
    for (int rp = 0; rp < 6; rp++) {
      int nn2 = rp * 8 + nb;
      float4 xa = ((const float4*)X[nn2])[kc * 2 + 0];
      float4 xb = ((const float4*)X[nn2])[kc * 2 + 1];
      acc[rp].x += xa.x * w4r[0].x + xa.y * w4r[1].x + xa.z * w4r[2].x + xa.w * w4r[3].x
                 + xb.x * w4r[4].x + xb.y * w4r[5].x + xb.z * w4r[6].x + xb.w * w4r[7].x;
      acc[rp].y += xa.x * w4r[0].y + xa.y * w4r[1].y + xa.z * w4r[2].y + xa.w * w4r[3].y
                 + xb.x * w4r[4].y + xb.y * w4r[5].y + xb.z * w4r[6].y + xb.w * w4r[7].y;
      acc[rp].z += xa.x * w4r[0].z + xa.y * w4r[1].z + xa.z * w4r[2].z + xa.w * w4r[3].z
                 + xb.x * w4r[4].z + xb.y * w4r[5].z + xb.z * w4r[6].z + xb.w * w4r[7].z;
      acc[rp].w += xa.x * w4r[0].w + xa.y * w4r[1].w + xa.z * w4r[2].w + xa.w * w4r[3].w
                 + xb.x * w4r[4].w + xb.y * w4r[5].w + xb.z * w4r[6].w + xb.w * w4r[7].w;
    }
  }
  float* xo = xw + ((size_t)t * BNR + b * N) * 128;
#pragma unroll
  for (int rp = 0; rp < 6; rp++) {
    int nn2 = rp * 8 + nb;
    nt_store4(acc[rp], xo + nn2 * 128 + g4 * 4);
  }
}

extern "C" void kernel_launch(void* const* d_in, const int* in_sizes, int n_in,
                              void* d_out, int out_size, void* d_ws, size_t ws_size,
                              hipStream_t stream)
{
  const float* feat     = (const float*)d_in[0];
  const float* phi_w1   = (const float*)d_in[1];
  const float* phi_b1   = (const float*)d_in[2];
  const float* phi_w2   = (const float*)d_in[3];
  const float* phi_b2   = (const float*)d_in[4];
  const float* spa_wih  = (const float*)d_in[5];
  const float* spa_whh  = (const float*)d_in[6];
  const float* spa_bih  = (const float*)d_in[7];
  const float* spa_bhh  = (const float*)d_in[8];
  const float* bn_gamma = (const float*)d_in[9];
  const float* bn_beta  = (const float*)d_in[10];
  const float* gat1_w   = (const float*)d_in[11];
  const float* gat1_a   = (const float*)d_in[12];
  const float* gat1_b   = (const float*)d_in[13];
  const float* gat2_w   = (const float*)d_in[14];
  const float* gat2_a   = (const float*)d_in[15];
  const float* gat2_b   = (const float*)d_in[16];
  const float* temp_wih = (const float*)d_in[17];
  const float* temp_whh = (const float*)d_in[18];
  const float* temp_bih = (const float*)d_in[19];
  const float* temp_bhh = (const float*)d_in[20];
  float* out = (float*)d_out;

  float* xw     = (float*)d_ws;                     // T*BNR*128 = 50.33M floats (shared xw1/xw2)
  float* bnpart = xw + (size_t)T * BNR * 128;       // T*BNP*64
  float* sctab  = bnpart + (size_t)T * BNP * 64;    // T*64

  k_phi <<<(B * T * N) / 256, 256, 0, stream>>>(feat, phi_w1, phi_b1, phi_w2, phi_b2, spa_wih, xw);
  k_lstm<0><<<BNR / 2, 256, 0, stream>>>(xw, spa_whh, spa_bih, spa_bhh, out);
  k_bn1 <<<dim3(T, BNP), 256, 0, stream>>>(out, bnpart);
  k_bn2 <<<T, 32, 0, stream>>>(bnpart, bn_gamma, bn_beta, sctab);
  k_gat <<<NG, 256, 0, stream>>>(out, sctab, gat1_w, gat1_a, gat1_b, gat2_w, gat2_a, gat2_b, temp_wih, xw);
  k_lstm<1><<<BNR / 2, 256, 0, stream>>>(xw, temp_whh, temp_bih, temp_bhh, out);
}

// Round 12
// 537.663 us; speedup vs baseline: 1.9206x; 1.9206x over previous
//
#include <hip/hip_runtime.h>

constexpr int B = 64, T = 128, M = 8, KLEAF = 5, KR = 6, N = 48, E = 16, H = 32;
constexpr int BNR = B * N;              // 3072 rows
constexpr int NG  = B * T;              // 8192 graphs
constexpr int BNP = 16;                 // BN stat partitions
constexpr long long R_SIZE = (long long)B * T * N * H;  // 12582912

#define DEVI __device__ __forceinline__

typedef float nf4 __attribute__((ext_vector_type(4)));   // native vec4 for NT builtins

DEVI float frcp(float x) { return __builtin_amdgcn_rcpf(x); }
DEVI float sigm(float x) { return frcp(1.f + __expf(-x)); }
DEVI float tanh_(float x) {
  float a = __expf(2.f * fabsf(x));
  float r = 1.f - 2.f * frcp(a + 1.f);
  return x >= 0.f ? r : -r;
}

DEVI void nt_store4(const float4& v, float* p) {
  nf4 t; t.x = v.x; t.y = v.y; t.z = v.z; t.w = v.w;
  __builtin_nontemporal_store(t, (nf4*)p);
}

// ------ K1: root agg + phi MLP + fused XW1 = v @ spa_wih^T → xw (T,BNR,128) --
// xw stores CACHED: per-lane-row 512B-strided float4s need L2 write-combining.
// (R11 post-mortem: NT here = 3.9x HBM write amplification, 522 us.)
__global__ __launch_bounds__(256, 4) void k_phi(
    const float* __restrict__ feat, const float* __restrict__ w1,
    const float* __restrict__ b1, const float* __restrict__ w2,
    const float* __restrict__ b2, const float* __restrict__ wih,
    float* __restrict__ xw)
{
  __shared__ float wT[E][128];           // wT[e][g] = wih[g*E+e]  (8 KB)
  int tid = threadIdx.x;
  for (int i = tid; i < E * 128; i += 256) {
    int e = i >> 7, g = i & 127;
    wT[e][g] = wih[g * E + e];
  }
  int gid = blockIdx.x * 256 + tid;      // grid is exact: B*T*N = 1536*256
  int nn = gid % N;
  int bt = gid / N;
  int m = nn / KR, k = nn % KR;
  int t = bt % T, b = bt / T;
  const float* fp = feat + ((size_t)bt * M + m) * (KLEAF * 3);
  float x0, x1, x2;
  if (k < KLEAF) {
    x0 = fp[k * 3 + 0]; x1 = fp[k * 3 + 1]; x2 = fp[k * 3 + 2];
  } else {
    float sx = 0.f, sy = 0.f, sw = 0.f, av = 0.f;
#pragma unroll
    for (int kp = 0; kp < KLEAF; kp++) {
      float fx = fp[kp * 3], fy = fp[kp * 3 + 1], fv = fp[kp * 3 + 2];
      float w = fv > 0.5f ? 1.f : 0.f;
      sx += fx * w; sy += fy * w; sw += w; av = fmaxf(av, w);
    }
    float dn = fmaxf(sw, 1.f);
    x0 = sx / dn; x1 = sy / dn; x2 = av;
  }
  float hd[E];
#pragma unroll
  for (int e = 0; e < E; e++) {
    float v = b1[e] + x0 * w1[0 * E + e] + x1 * w1[1 * E + e] + x2 * w1[2 * E + e];
    hd[e] = v > 0.f ? v : 0.f;
  }
  float vv[E];
#pragma unroll
  for (int e2 = 0; e2 < E; e2++) {
    float acc = b2[e2];
#pragma unroll
    for (int e = 0; e < E; e++) acc += hd[e] * w2[e * E + e2];
    vv[e2] = acc;
  }
  __syncthreads();
  // xw row = v @ wT  (128 gates, 4 passes of 32)
  float* xo = xw + ((size_t)t * BNR + b * N + nn) * 128;
  for (int pass = 0; pass < 4; pass++) {
    float4 a4[8];
#pragma unroll
    for (int c = 0; c < 8; c++) a4[c] = make_float4(0.f, 0.f, 0.f, 0.f);
#pragma unroll
    for (int e = 0; e < E; e++) {
      float ve = vv[e];
      const float4* wr = (const float4*)&wT[e][pass * 32];
#pragma unroll
      for (int c = 0; c < 8; c++) {
        float4 w4 = wr[c];
        a4[c].x += ve * w4.x; a4[c].y += ve * w4.y;
        a4[c].z += ve * w4.z; a4[c].w += ve * w4.w;
      }
    }
#pragma unroll
    for (int c = 0; c < 8; c++) ((float4*)xo)[pass * 8 + c] = a4[c];
  }
}

// ------- K2/K5: LSTM recurrence only (x-projection precomputed in xw) --------
// xw reads NT (one-shot stream, wave-contiguous 256B). php stores NT (4B/lane,
// 128B contiguous per half-wave). pr re-read by bn/gat -> cached.
template <int MODE>
__global__ __launch_bounds__(256, 6) void k_lstm(
    const float* __restrict__ xw, const float* __restrict__ whh,
    const float* __restrict__ bih, const float* __restrict__ bhh,
    float* __restrict__ dout)
{
  int tid = threadIdx.x;
  int wave = tid >> 6;
  int pr_ = wave >> 1;          // row within block (0,1)
  int wsel = wave & 1;          // 0: {i,f}  1: {g,o}
  int lane = tid & 63;
  int j = lane & 31, hi = lane >> 5;
  int row = blockIdx.x * 2 + pr_;
  int b = row / N, n = row % N;
  int gate = wsel * 64 + hi * 32 + j;

  float Wh[32];
#pragma unroll
  for (int k = 0; k < 32; k++) Wh[k] = whh[gate * 32 + k];
  float bs = bih[gate] + bhh[gate];

  __shared__ __align__(16) float hl[4][32];   // per-wave h copy
  __shared__ float gx[2][2][2][2][32];        // [pr][par][wsel][hi][j]
  if (hi == 0) hl[wave][j] = 0.f;             // own-wave init, in-order DS

  const float* xpt = xw + (size_t)row * 128 + gate;
  float xc = __builtin_nontemporal_load(xpt); // t = 0
  xpt += (size_t)BNR * 128;

  float c = 0.f;
  float* prp = dout + ((size_t)b * T * N + n) * H + j;
  float* php = dout + R_SIZE + ((size_t)b * T * N + n) * 2 * H + (MODE == 1 ? H : 0) + j;

  for (int t = 0; t < T; t++) {
    int par = t & 1;
    float xn = 0.f;
    if (t < T - 1) {
      xn = __builtin_nontemporal_load(xpt);
      xpt += (size_t)BNR * 128;
    }
    float a0 = bs + xc, a1 = 0.f, a2 = 0.f, a3 = 0.f;
    const float4* hp4 = (const float4*)hl[wave];
#pragma unroll
    for (int q = 0; q < 8; q++) {
      float4 hv = hp4[q];                     // ds_read_b128 broadcast
      a0 += Wh[4 * q + 0] * hv.x; a1 += Wh[4 * q + 1] * hv.y;
      a2 += Wh[4 * q + 2] * hv.z; a3 += Wh[4 * q + 3] * hv.w;
    }
    float a = (a0 + a1) + (a2 + a3);
    float act = (wsel == 0) ? sigm(a) : (hi ? sigm(a) : tanh_(a));
    gx[pr_][par][wsel][hi][j] = act;
    __syncthreads();
    if (hi == 0) {
      float iv = gx[pr_][par][0][0][j];
      float fv = gx[pr_][par][0][1][j];
      float gv = gx[pr_][par][1][0][j];
      float ov = gx[pr_][par][1][1][j];
      c = fv * c + iv * gv;
      float hnew = ov * tanh_(c);
      hl[wave][j] = hnew;                     // own-wave write
      if (wsel == 0) {
        if (MODE == 0) {
          *prp = hnew;
          __builtin_nontemporal_store(hnew, php);
        } else {
          __builtin_nontemporal_store(hnew, php);
        }
      }
    }
    xc = xn;
    prp += N * H; php += N * 2 * H;
  }
}

// ---------------- K3a: BN partial stats per (t, partition) -------------------
__global__ __launch_bounds__(256) void k_bn1(
    const float* __restrict__ r, float* __restrict__ part)
{
  int t = blockIdx.x, p = blockIdx.y;
  int c = threadIdx.x & 31, rg = threadIdx.x >> 5;
  constexpr int RPP = BNR / BNP;   // 192 rows per partition
  float s = 0.f, s2 = 0.f;
  for (int row = p * RPP + rg; row < (p + 1) * RPP; row += 8) {
    int b = row / N, n = row % N;
    float x = r[((size_t)b * T + t) * N * H + (size_t)n * H + c];
    s += x; s2 += x * x;
  }
  __shared__ float sm[2][8][32];
  sm[0][rg][c] = s; sm[1][rg][c] = s2;
  __syncthreads();
  if (rg == 0) {
    float ss = 0.f, ss2 = 0.f;
#pragma unroll
    for (int i = 0; i < 8; i++) { ss += sm[0][i][c]; ss2 += sm[1][i][c]; }
    part[((size_t)t * BNP + p) * 64 + c] = ss;
    part[((size_t)t * BNP + p) * 64 + 32 + c] = ss2;
  }
}

// ---------------- K3b: finalize BN scale/shift table (T, 2, 32) --------------
__global__ void k_bn2(
    const float* __restrict__ part, const float* __restrict__ gamma,
    const float* __restrict__ beta, float* __restrict__ sctab)
{
  int t = blockIdx.x, c = threadIdx.x;   // 32 threads
  float ss = 0.f, ss2 = 0.f;
#pragma unroll
  for (int p = 0; p < BNP; p++) {
    ss  += part[((size_t)t * BNP + p) * 64 + c];
    ss2 += part[((size_t)t * BNP + p) * 64 + 32 + c];
  }
  float mu = ss * (1.f / BNR);
  float var = ss2 * (1.f / BNR) - mu * mu;
  float rstd = rsqrtf(var + 1e-5f);
  float sc = gamma[c] * rstd;
  sctab[t * 64 + c] = sc;
  sctab[t * 64 + 32 + c] = beta[c] - mu * sc;
}

// --- K4: BN-apply + 2x GAT + fused XW2 = rhat @ temp_wih^T → xw (T,BNR,128) --
// (256,2): VGPR cap 256 kills the R9 epilogue spill. Epilogue NT stores are
// wave-contiguous (32 lanes x float4 = one 512B row) -> coalesce cleanly.
__global__ __launch_bounds__(256, 2) void k_gat(
    const float* __restrict__ r, const float* __restrict__ sctab,
    const float* __restrict__ w1, const float* __restrict__ a1, const float* __restrict__ bg1,
    const float* __restrict__ w2, const float* __restrict__ a2, const float* __restrict__ bg2,
    const float* __restrict__ twih, float* __restrict__ xw)
{
  int g = blockIdx.x;          // b*T + t
  int b = g >> 7, t = g & 127;
  int tid = threadIdx.x;
  __shared__ float X[N][H];
  __shared__ float Hm[N][H + 1];   // padded: row-reads conflict-free
  __shared__ float Wl[H * H];
  __shared__ float wT2[H][128];    // wT2[k][g] = twih[g*32+k]  (16 KB)
  __shared__ float ssrc[N], sdst[N];
  __shared__ float alph[M][12];
  for (int i = tid; i < N * H; i += 256) {
    int cc = i & 31;
    ((float*)X)[i] = r[(size_t)g * N * H + i] * sctab[t * 64 + cc] + sctab[t * 64 + 32 + cc];
  }
  for (int i = tid; i < H * 128; i += 256) {
    int k = i >> 7, gg = i & 127;
    wT2[k][gg] = twih[gg * H + k];
  }
  const float* Ws[2] = {w1, w2};
  const float* As[2] = {a1, a2};
  const float* Bs[2] = {bg1, bg2};
  int oc = tid & 31, n0 = tid >> 5;
  for (int layer = 0; layer < 2; layer++) {
    const float* av = As[layer];
    const float* bias = Bs[layer];
    for (int i = tid; i < H * H; i += 256) Wl[i] = Ws[layer][i];
    __syncthreads();
    // h = X @ W  (48x32 @ 32x32)
#pragma unroll
    for (int rep = 0; rep < 6; rep++) {
      int n = n0 + rep * 8;
      float acc = 0.f;
#pragma unroll
      for (int kk = 0; kk < H; kk++) acc += X[n][kk] * Wl[kk * H + oc];
      Hm[n][oc] = acc;
    }
    __syncthreads();
    if (tid < N) {
      float as = 0.f, ad = 0.f;
#pragma unroll
      for (int kk = 0; kk < H; kk++) {
        float x = Hm[tid][kk];
        as += x * av[kk]; ad += x * av[H + kk];
      }
      ssrc[tid] = as; sdst[tid] = ad;
    }
    __syncthreads();
    if (tid < M) {   // softmax over each root's 12 incoming edges
      float ev[12];
      float sd = sdst[tid * KR + KR - 1];
#pragma unroll
      for (int kp = 0; kp < KLEAF; kp++) ev[kp] = ssrc[tid * KR + kp] + sd;
#pragma unroll
      for (int j = 0; j < 7; j++) {
        int mm = j < tid ? j : j + 1;
        ev[KLEAF + j] = ssrc[mm * KR + KR - 1] + sd;
      }
      float mx = -1e30f;
#pragma unroll
      for (int i = 0; i < 12; i++) {
        float e = ev[i]; e = e > 0.f ? e : 0.2f * e;
        ev[i] = e; mx = fmaxf(mx, e);
      }
      float s = 0.f;
#pragma unroll
      for (int i = 0; i < 12; i++) { float e = __expf(ev[i] - mx); ev[i] = e; s += e; }
      float inv = frcp(s);
#pragma unroll
      for (int i = 0; i < 12; i++) alph[tid][i] = ev[i] * inv;
    }
    __syncthreads();
    float hv[6];
#pragma unroll
    for (int rep = 0; rep < 6; rep++) {
      int n = n0 + rep * 8;
      int m2 = n / KR;
      float acc;
      if (n % KR == KR - 1) {      // root: attention-weighted sum of 12 srcs
        acc = 0.f;
#pragma unroll
        for (int kp = 0; kp < KLEAF; kp++) acc += alph[m2][kp] * Hm[m2 * KR + kp][oc];
#pragma unroll
        for (int j = 0; j < 7; j++) {
          int mm = j < m2 ? j : j + 1;
          acc += alph[m2][KLEAF + j] * Hm[mm * KR + KR - 1][oc];
        }
      } else {                      // leaf: single incoming edge, alpha == 1
        acc = Hm[m2 * KR + KR - 1][oc];
      }
      acc += bias[oc];
      hv[rep] = acc > 0.f ? acc : __expf(acc) - 1.f;   // elu
    }
    __syncthreads();
#pragma unroll
    for (int rep = 0; rep < 6; rep++) X[n0 + rep * 8][oc] = hv[rep];
    __syncthreads();
  }
  // XW2 epilogue: xw[t][b*N+n][0:128] = X[n][:] @ wT2  (rhat is in X)
  int g4 = tid & 31;            // float4 column 0..31
  int nb = tid >> 5;            // 0..7
  float4 acc[6];
#pragma unroll
  for (int rp = 0; rp < 6; rp++) acc[rp] = make_float4(0.f, 0.f, 0.f, 0.f);
  for (int kc = 0; kc < 4; kc++) {
    float4 w4r[8];
#pragma unroll
    for (int k8 = 0; k8 < 8; k8++) w4r[k8] = ((const float4*)wT2[kc * 8 + k8])[g4];
#pragma unroll
    for (int rp = 0; rp < 6; rp++) {
      int nn2 = rp * 8 + nb;
      float4 xa = ((const float4*)X[nn2])[kc * 2 + 0];
      float4 xb = ((const float4*)X[nn2])[kc * 2 + 1];
      acc[rp].x += xa.x * w4r[0].x + xa.y * w4r[1].x + xa.z * w4r[2].x + xa.w * w4r[3].x
                 + xb.x * w4r[4].x + xb.y * w4r[5].x + xb.z * w4r[6].x + xb.w * w4r[7].x;
      acc[rp].y += xa.x * w4r[0].y + xa.y * w4r[1].y + xa.z * w4r[2].y + xa.w * w4r[3].y
                 + xb.x * w4r[4].y + xb.y * w4r[5].y + xb.z * w4r[6].y + xb.w * w4r[7].y;
      acc[rp].z += xa.x * w4r[0].z + xa.y * w4r[1].z + xa.z * w4r[2].z + xa.w * w4r[3].z
                 + xb.x * w4r[4].z + xb.y * w4r[5].z + xb.z * w4r[6].z + xb.w * w4r[7].z;
      acc[rp].w += xa.x * w4r[0].w + xa.y * w4r[1].w + xa.z * w4r[2].w + xa.w * w4r[3].w
                 + xb.x * w4r[4].w + xb.y * w4r[5].w + xb.z * w4r[6].w + xb.w * w4r[7].w;
    }
  }
  float* xo = xw + ((size_t)t * BNR + b * N) * 128;
#pragma unroll
  for (int rp = 0; rp < 6; rp++) {
    int nn2 = rp * 8 + nb;
    nt_store4(acc[rp], xo + nn2 * 128 + g4 * 4);
  }
}

extern "C" void kernel_launch(void* const* d_in, const int* in_sizes, int n_in,
                              void* d_out, int out_size, void* d_ws, size_t ws_size,
                              hipStream_t stream)
{
  const float* feat     = (const float*)d_in[0];
  const float* phi_w1   = (const float*)d_in[1];
  const float* phi_b1   = (const float*)d_in[2];
  const float* phi_w2   = (const float*)d_in[3];
  const float* phi_b2   = (const float*)d_in[4];
  const float* spa_wih  = (const float*)d_in[5];
  const float* spa_whh  = (const float*)d_in[6];
  const float* spa_bih  = (const float*)d_in[7];
  const float* spa_bhh  = (const float*)d_in[8];
  const float* bn_gamma = (const float*)d_in[9];
  const float* bn_beta  = (const float*)d_in[10];
  const float* gat1_w   = (const float*)d_in[11];
  const float* gat1_a   = (const float*)d_in[12];
  const float* gat1_b   = (const float*)d_in[13];
  const float* gat2_w   = (const float*)d_in[14];
  const float* gat2_a   = (const float*)d_in[15];
  const float* gat2_b   = (const float*)d_in[16];
  const float* temp_wih = (const float*)d_in[17];
  const float* temp_whh = (const float*)d_in[18];
  const float* temp_bih = (const float*)d_in[19];
  const float* temp_bhh = (const float*)d_in[20];
  float* out = (float*)d_out;

  float* xw     = (float*)d_ws;                     // T*BNR*128 = 50.33M floats (shared xw1/xw2)
  float* bnpart = xw + (size_t)T * BNR * 128;       // T*BNP*64
  float* sctab  = bnpart + (size_t)T * BNP * 64;    // T*64

  k_phi <<<(B * T * N) / 256, 256, 0, stream>>>(feat, phi_w1, phi_b1, phi_w2, phi_b2, spa_wih, xw);
  k_lstm<0><<<BNR / 2, 256, 0, stream>>>(xw, spa_whh, spa_bih, spa_bhh, out);
  k_bn1 <<<dim3(T, BNP), 256, 0, stream>>>(out, bnpart);
  k_bn2 <<<T, 32, 0, stream>>>(bnpart, bn_gamma, bn_beta, sctab);
  k_gat <<<NG, 256, 0, stream>>>(out, sctab, gat1_w, gat1_a, gat1_b, gat2_w, gat2_a, gat2_b, temp_wih, xw);
  k_lstm<1><<<BNR / 2, 256, 0, stream>>>(xw, temp_whh, temp_bih, temp_bhh, out);
}